// Round 9
// baseline (362.481 us; speedup 1.0000x reference)
//
#include <hip/hip_runtime.h>
#include <hip/hip_bf16.h>

#define T_STEPS 256
#define BATCH   512
#define HID     128
#define TBROWS  (T_STEPS * BATCH)
#define XH_STRIDE 32          // xcat as f16, 32 ushorts per row (24 used)

typedef short  bh8   __attribute__((ext_vector_type(8)));   // 8 bf16 (MFMA A/B frag)
typedef _Float16 h8  __attribute__((ext_vector_type(8)));   // 8 f16  (MFMA A/B frag)
typedef float  f32x4 __attribute__((ext_vector_type(4)));   // MFMA C/D frag

__device__ __forceinline__ unsigned short f2bf_bits(float x) {
    union { float f; unsigned int u; } a; a.f = x;
    unsigned int r = a.u + 0x7fffu + ((a.u >> 16) & 1u);   // RNE
    return (unsigned short)(r >> 16);
}
__device__ __forceinline__ unsigned short f2h_bits(float x) {
    union { _Float16 h; unsigned short u; } z; z.h = (_Float16)x; return z.u;
}
__device__ __forceinline__ unsigned int pack2h(float a, float b) {
    union { _Float16 h[2]; unsigned int u; } z;
    z.h[0] = (_Float16)a; z.h[1] = (_Float16)b; return z.u;
}
__device__ __forceinline__ unsigned int pack2bf(float a, float b) {
    return (unsigned int)f2bf_bits(a) | ((unsigned int)f2bf_bits(b) << 16);
}

#if __has_builtin(__builtin_amdgcn_rcpf)
__device__ __forceinline__ float frcp(float x) { return __builtin_amdgcn_rcpf(x); }
#else
__device__ __forceinline__ float frcp(float x) { return 1.0f / x; }
#endif
#if __has_builtin(__builtin_amdgcn_exp2f)
__device__ __forceinline__ float fexp2(float x) { return __builtin_amdgcn_exp2f(x); }
#else
__device__ __forceinline__ float fexp2(float x) { return __expf(x * 0.6931471806f); }
#endif
#define LOG2E 1.442695041f
__device__ __forceinline__ float sigf(float x) {
    return frcp(1.0f + fexp2(-x * LOG2E));
}
__device__ __forceinline__ float tanh_fast(float x) {
    return fmaf(-2.0f, frcp(1.0f + fexp2(x * (2.0f * LOG2E))), 1.0f);
}

// ds_swizzle BitMode: src_lane = lane & 0xF (within each 32-half)
__device__ __forceinline__ float swz16(float v) {
    return __int_as_float(
        __builtin_amdgcn_ds_swizzle(__float_as_int(v), 0x000F));
}

// Raw workgroup barrier that drains ONLY LDS ops (lgkmcnt), leaving global
// stores/loads in flight (prefetch loads & out-store acks keep flowing).
__device__ __forceinline__ void barrier_lds_only() {
    asm volatile("s_waitcnt lgkmcnt(0)" ::: "memory");
    __builtin_amdgcn_s_barrier();
    asm volatile("" ::: "memory");
}

// ===========================================================================
// Prep (unchanged): bf16 frag blobs for MLP, f16 frag blob for the LSTM
// combined weight Wc[512x160] (k<128 Whh, 128<=k<152 Wih, else 0), fused
// gate bias. Frag layout (A and B share the pattern on 16x16x32):
//   blob[(tile*KT + kt)*512 + lane*8 + j] = W[tile*16 + (lane&15)][kt*32 + (lane>>4)*8 + j]
// ===========================================================================
__device__ __forceinline__ void fragstore(unsigned short* dst, const float* W,
                                          int i, int NT, int Kreal) {
    const int j    = i & 7;
    const int lane = (i >> 3) & 63;
    const int ts   = i >> 9;
    const int nt   = ts % NT;
    const int ks   = ts / NT;
    const int n = nt * 16 + (lane & 15);
    const int k = ks * 32 + (lane >> 4) * 8 + j;
    dst[i] = (k < Kreal) ? f2bf_bits(W[n * Kreal + k]) : (unsigned short)0;
}

#define NE1 8192     // 16 tiles * 512
#define NE2 65536    // 8 kt * 16 tiles * 512
#define NE3 32768    // 8 * 8 * 512
#define NE4 2048     // 4 * 1 * 512
#define NWC 81920    // 32 mtiles * 5 ktiles * 64 * 8  (LSTM frags, f16)
#define NBS 512
#define PREP_TOTAL (NE1 + NE2 + NE3 + NE4 + NWC + NBS)   // 190976

__global__ __launch_bounds__(256) void prep_kernel(
    const float* __restrict__ W1, const float* __restrict__ W2,
    const float* __restrict__ W3, const float* __restrict__ W4,
    const float* __restrict__ Wih, const float* __restrict__ bih,
    const float* __restrict__ Whh, const float* __restrict__ bhh,
    unsigned short* __restrict__ w1f, unsigned short* __restrict__ w2f,
    unsigned short* __restrict__ w3f, unsigned short* __restrict__ w4f,
    unsigned short* __restrict__ wcf, float* __restrict__ bsum)
{
    int i = blockIdx.x * 256 + threadIdx.x;
    if (i < NE1) { fragstore(w1f, W1, i, 16, 25); return; }
    i -= NE1;
    if (i < NE2) { fragstore(w2f, W2, i, 16, 256); return; }
    i -= NE2;
    if (i < NE3) { fragstore(w3f, W3, i, 8, 256); return; }
    i -= NE3;
    if (i < NE4) { fragstore(w4f, W4, i, 1, 128); return; }
    i -= NE4;
    if (i < NWC) {
        const int j    = i & 7;
        const int lane = (i >> 3) & 63;
        const int ts   = i >> 9;          // mt*5 + kt
        const int mt   = ts / 5;
        const int kt   = ts - mt * 5;
        const int m = mt * 16 + (lane & 15);
        const int k = kt * 32 + (lane >> 4) * 8 + j;
        float v = 0.0f;
        if (k < 128)      v = Whh[m * 128 + k];
        else if (k < 152) v = Wih[m * 24 + (k - 128)];
        wcf[i] = f2h_bits(v);
        return;
    }
    i -= NWC;
    if (i < NBS) bsum[i] = bih[i] + bhh[i];
}

// ===========================================================================
// Encoder v5 (persistent blocks, register-resident weights):
// 256 blocks (1/CU) x 512 thr (8 waves, 2/SIMD); block owns 512 samples =
// 8 tiles of 64. Wave w owns neuron slices: L1/L2 mtiles {2w,2w+1}, L3
// mtile w, L4 waves 0..3 (one sample-group each). Weight frags live in
// VGPRs for the WHOLE kernel (120 VGPR) -> zero weight reloads per tile
// (v4 re-read ~208 KB/block/tile from L2 -- the dominant exposed latency).
// Biases folded into MFMA C-init. img prefetched one tile ahead into regs;
// lgkm-only barriers keep those loads in flight. 4 barriers/tile.
// ===========================================================================
#define ASTRIDE 264
#define ETILES 8
#define EBLK   512

__device__ __forceinline__ void enc_tile(
    const float* __restrict__ img, unsigned short* __restrict__ xcat_h,
    unsigned short (*bufA)[ASTRIDE], unsigned short (*bufB)[ASTRIDE],
    const bh8 (&wf1)[2], const bh8 (&wf2)[8][2], const bh8 (&wf3)[8],
    const bh8 (&wf4)[4],
    const f32x4 (&bi1)[2], const f32x4 (&bi2)[2], const f32x4& bi3,
    const f32x4& bi4,
    float (&fin)[4][8], float (&fnx)[4][8],
    int row0, int nrow0, bool pf, int w, int n, int quad)
{
    // convert current tile's img to bf16 B-frags (waits on fin's loads,
    // which were issued one full tile ago)
    bh8 bimg[4];
    #pragma unroll
    for (int sg = 0; sg < 4; ++sg)
        #pragma unroll
        for (int j = 0; j < 8; ++j)
            bimg[sg][j] = (short)f2bf_bits(fin[sg][j] * (1.0f / 255.0f));

    // prefetch next tile's img (predicated; masked lanes keep 0)
    if (pf) {
        #pragma unroll
        for (int sg = 0; sg < 4; ++sg) {
            const size_t grow = (size_t)(nrow0 + sg * 16 + n);
            #pragma unroll
            for (int j = 0; j < 8; ++j) {
                const int k = quad * 8 + j;
                fnx[sg][j] = (k < 25) ? img[grow * 25 + k] : 0.0f;
            }
        }
    }

    // ---- L1: 25(pad32) -> 256; wave w owns mtiles 2w,2w+1 -> bufA ----
    #pragma unroll
    for (int mt = 0; mt < 2; ++mt) {
        f32x4 acc[4];
        #pragma unroll
        for (int sg = 0; sg < 4; ++sg)
            acc[sg] = __builtin_amdgcn_mfma_f32_16x16x32_bf16(
                wf1[mt], bimg[sg], bi1[mt], 0, 0, 0);
        #pragma unroll
        for (int sg = 0; sg < 4; ++sg) {
            uint2 pk;
            pk.x = pack2bf(fmaxf(acc[sg][0], 0.0f), fmaxf(acc[sg][1], 0.0f));
            pk.y = pack2bf(fmaxf(acc[sg][2], 0.0f), fmaxf(acc[sg][3], 0.0f));
            *reinterpret_cast<uint2*>(
                &bufA[sg * 16 + n][(2 * w + mt) * 16 + quad * 4]) = pk;
        }
    }
    barrier_lds_only();

    // ---- L2: 256 -> 256; read bufA, write bufB ----
    {
        f32x4 a2[2][4];
        #pragma unroll
        for (int mt = 0; mt < 2; ++mt)
            #pragma unroll
            for (int sg = 0; sg < 4; ++sg) a2[mt][sg] = bi2[mt];
        #pragma unroll
        for (int kt = 0; kt < 8; ++kt) {
            bh8 b[4];
            #pragma unroll
            for (int sg = 0; sg < 4; ++sg)
                b[sg] = *reinterpret_cast<const bh8*>(
                    &bufA[sg * 16 + n][kt * 32 + quad * 8]);
            #pragma unroll
            for (int mt = 0; mt < 2; ++mt)
                #pragma unroll
                for (int sg = 0; sg < 4; ++sg)
                    a2[mt][sg] = __builtin_amdgcn_mfma_f32_16x16x32_bf16(
                        wf2[kt][mt], b[sg], a2[mt][sg], 0, 0, 0);
        }
        #pragma unroll
        for (int mt = 0; mt < 2; ++mt)
            #pragma unroll
            for (int sg = 0; sg < 4; ++sg) {
                uint2 pk;
                pk.x = pack2bf(fmaxf(a2[mt][sg][0], 0.0f), fmaxf(a2[mt][sg][1], 0.0f));
                pk.y = pack2bf(fmaxf(a2[mt][sg][2], 0.0f), fmaxf(a2[mt][sg][3], 0.0f));
                *reinterpret_cast<uint2*>(
                    &bufB[sg * 16 + n][(2 * w + mt) * 16 + quad * 4]) = pk;
            }
    }
    barrier_lds_only();

    // ---- L3: 256 -> 128; read bufB, write bufA (cols 0..127) ----
    {
        f32x4 a3[4];
        #pragma unroll
        for (int sg = 0; sg < 4; ++sg) a3[sg] = bi3;
        #pragma unroll
        for (int kt = 0; kt < 8; ++kt) {
            bh8 b[4];
            #pragma unroll
            for (int sg = 0; sg < 4; ++sg)
                b[sg] = *reinterpret_cast<const bh8*>(
                    &bufB[sg * 16 + n][kt * 32 + quad * 8]);
            #pragma unroll
            for (int sg = 0; sg < 4; ++sg)
                a3[sg] = __builtin_amdgcn_mfma_f32_16x16x32_bf16(
                    wf3[kt], b[sg], a3[sg], 0, 0, 0);
        }
        #pragma unroll
        for (int sg = 0; sg < 4; ++sg) {
            uint2 pk;
            pk.x = pack2bf(fmaxf(a3[sg][0], 0.0f), fmaxf(a3[sg][1], 0.0f));
            pk.y = pack2bf(fmaxf(a3[sg][2], 0.0f), fmaxf(a3[sg][3], 0.0f));
            *reinterpret_cast<uint2*>(
                &bufA[sg * 16 + n][w * 16 + quad * 4]) = pk;
        }
    }
    barrier_lds_only();

    // ---- L4: 128 -> 16; waves 0..3, sample-group = w; write xcat (f16) ----
    if (w < 4) {
        f32x4 a4 = bi4;
        #pragma unroll
        for (int kt = 0; kt < 4; ++kt) {
            const bh8 b = *reinterpret_cast<const bh8*>(
                &bufA[w * 16 + n][kt * 32 + quad * 8]);
            a4 = __builtin_amdgcn_mfma_f32_16x16x32_bf16(wf4[kt], b, a4, 0, 0, 0);
        }
        const int grow = row0 + w * 16 + n;
        uint2 pk;
        pk.x = pack2h(fmaxf(a4[0], 0.0f), fmaxf(a4[1], 0.0f));
        pk.y = pack2h(fmaxf(a4[2], 0.0f), fmaxf(a4[3], 0.0f));
        *reinterpret_cast<uint2*>(xcat_h + (size_t)grow * XH_STRIDE + quad * 4) = pk;
    }
    barrier_lds_only();   // protect bufA before next tile's L1 writes
}

__global__ __launch_bounds__(512, 2) void encoder_kernel(
    const float* __restrict__ img,
    const float* __restrict__ loc,
    const float* __restrict__ msg,
    const int*   __restrict__ done,
    const float* __restrict__ B1, const float* __restrict__ B2,
    const float* __restrict__ B3, const float* __restrict__ B4,
    const float* __restrict__ Wl, const float* __restrict__ Bl,
    const float* __restrict__ Wm, const float* __restrict__ Bm,
    const unsigned short* __restrict__ w1f, const unsigned short* __restrict__ w2f,
    const unsigned short* __restrict__ w3f, const unsigned short* __restrict__ w4f,
    unsigned short* __restrict__ xcat_h)
{
    __shared__ __align__(16) unsigned short bufA[64][ASTRIDE];
    __shared__ __align__(16) unsigned short bufB[64][ASTRIDE];

    const int tid  = threadIdx.x;
    const int w    = tid >> 6;
    const int lane = tid & 63;
    const int n    = lane & 15;
    const int quad = lane >> 4;
    const int blk0 = blockIdx.x * EBLK;

    // loc/msg encoders: all 512 samples of this block, 1 thread each
    {
        const int grow = blk0 + tid;
        const float l0 = loc[(size_t)grow * 2 + 0] * 0.1f;
        const float l1 = loc[(size_t)grow * 2 + 1] * 0.1f;
        #pragma unroll
        for (int c = 0; c < 4; ++c)
            xcat_h[(size_t)grow * XH_STRIDE + 16 + c] =
                f2h_bits(fmaf(Wl[c * 2 + 0], l0, fmaf(Wl[c * 2 + 1], l1, Bl[c])));
        const float mm = (1.0f - (float)done[grow]) * msg[grow];
        #pragma unroll
        for (int c = 0; c < 4; ++c)
            xcat_h[(size_t)grow * XH_STRIDE + 20 + c] =
                f2h_bits(fmaxf(fmaf(Wm[c], mm, Bm[c]), 0.0f));
    }

    // initial img load (tile 0) — issue FIRST (HBM latency)
    float fA[4][8], fB[4][8];
    #pragma unroll
    for (int sg = 0; sg < 4; ++sg) {
        const size_t grow = (size_t)(blk0 + sg * 16 + n);
        #pragma unroll
        for (int j = 0; j < 8; ++j) {
            const int k = quad * 8 + j;
            fA[sg][j] = (k < 25) ? img[grow * 25 + k] : 0.0f;
        }
    }

    // persistent weight frags (L2-cache reads, once per kernel)
    bh8 wf1[2], wf2[8][2], wf3[8], wf4[4];
    #pragma unroll
    for (int mt = 0; mt < 2; ++mt)
        wf1[mt] = *reinterpret_cast<const bh8*>(
            w1f + (size_t)((2 * w + mt) * 64 + lane) * 8);
    #pragma unroll
    for (int kt = 0; kt < 8; ++kt)
        #pragma unroll
        for (int mt = 0; mt < 2; ++mt)
            wf2[kt][mt] = *reinterpret_cast<const bh8*>(
                w2f + (size_t)((kt * 16 + 2 * w + mt) * 64 + lane) * 8);
    #pragma unroll
    for (int kt = 0; kt < 8; ++kt)
        wf3[kt] = *reinterpret_cast<const bh8*>(
            w3f + (size_t)((kt * 8 + w) * 64 + lane) * 8);
    #pragma unroll
    for (int kt = 0; kt < 4; ++kt)
        wf4[kt] = *reinterpret_cast<const bh8*>(
            w4f + (size_t)(kt * 64 + lane) * 8);

    // biases as MFMA C-init vectors (C rows = quad*4+r)
    f32x4 bi1[2], bi2[2], bi3, bi4;
    #pragma unroll
    for (int mt = 0; mt < 2; ++mt) {
        float4 v = *reinterpret_cast<const float4*>(B1 + (2 * w + mt) * 16 + quad * 4);
        bi1[mt] = (f32x4){v.x, v.y, v.z, v.w};
        float4 u = *reinterpret_cast<const float4*>(B2 + (2 * w + mt) * 16 + quad * 4);
        bi2[mt] = (f32x4){u.x, u.y, u.z, u.w};
    }
    {
        float4 v = *reinterpret_cast<const float4*>(B3 + w * 16 + quad * 4);
        bi3 = (f32x4){v.x, v.y, v.z, v.w};
        float4 u = *reinterpret_cast<const float4*>(B4 + quad * 4);
        bi4 = (f32x4){u.x, u.y, u.z, u.w};
    }

    // tile loop, unrolled by 2 for static fA/fB ping-pong (rule: no
    // runtime-indexed register arrays)
    #pragma unroll 1
    for (int t = 0; t < ETILES; t += 2) {
        enc_tile(img, xcat_h, bufA, bufB, wf1, wf2, wf3, wf4,
                 bi1, bi2, bi3, bi4, fA, fB,
                 blk0 + t * 64, blk0 + (t + 1) * 64, true, w, n, quad);
        enc_tile(img, xcat_h, bufA, bufB, wf1, wf2, wf3, wf4,
                 bi1, bi2, bi3, bi4, fB, fA,
                 blk0 + (t + 1) * 64, blk0 + (t + 2) * 64, t + 2 < ETILES,
                 w, n, quad);
    }
}

// ===========================================================================
// LSTM scan v8 (unchanged, ~197 us): 256 blocks x 2 cols, 512 threads
// (8 waves). Swapped-operand MFMA, predicated 8-lane hx frag loads,
// ds_swizzle gate redistribution, full x/done LDS preload, lgkm-only
// barrier. Near structural floor for this decomposition (~40 MFMA/SIMD/step
// at ~17-19 cy + serial chain).
// ===========================================================================
#define COLS 2

__global__ __launch_bounds__(512) void lstm_kernel(
    const unsigned short* __restrict__ xcat_h,
    const int*   __restrict__ done,
    const float* __restrict__ h0,
    const float* __restrict__ c0,
    const unsigned short* __restrict__ wcf,   // frag blob [32][5][64][8] f16
    const float* __restrict__ bsum,           // [512] = bih + bhh
    float* __restrict__ out)
{
    __shared__ __align__(16) unsigned short xls[T_STEPS][COLS][32];  // 32 KB
    __shared__ __align__(16) unsigned short hx[2][COLS][HID];        // 1 KB
    __shared__ int dls[T_STEPS][COLS];                               // 2 KB

    const int tid  = threadIdx.x;
    const int w    = tid >> 6;        // wave 0..7
    const int lane = tid & 63;
    const int n    = lane & 15;
    const int quad = lane >> 4;
    const int bb   = blockIdx.x * COLS;

    // ---- one-time preload: x sequence (k=128..159 of the frag, pad zeroed)
    for (int i = tid; i < T_STEPS * COLS * 16; i += 512) {
        const int dw = i & 15;            // dword within 32-short row
        const int rc = i >> 4;            // step*COLS + col
        const int st = rc >> 1, cl = rc & 1;
        unsigned int v = 0u;
        if (dw < 12)
            v = *reinterpret_cast<const unsigned int*>(
                xcat_h + (size_t)(st * BATCH + bb + cl) * XH_STRIDE + dw * 2);
        *reinterpret_cast<unsigned int*>(&xls[st][cl][dw * 2]) = v;
    }
    // ---- one-time preload: done sequence
    if (tid < T_STEPS * COLS) {
        const int st = tid >> 1, cl = tid & 1;
        dls[st][cl] = done[st * BATCH + bb + cl];
    }

    // weight frags (B operand of the swapped MFMA): wave w covers units
    // w*16..w*16+15 for gate g via mtile g*8+w.  (80 VGPRs)
    h8 wf[4][5];
    #pragma unroll
    for (int g = 0; g < 4; ++g)
        #pragma unroll
        for (int kt = 0; kt < 5; ++kt)
            wf[g][kt] = *reinterpret_cast<const h8*>(
                wcf + (size_t)(((g * 8 + w) * 5 + kt) * 64 + lane) * 8);

    // bias C-init: C col (=lane&15) is the unit dim -> per-lane splat
    const int unit = w * 16 + n;
    f32x4 bini[4];
    #pragma unroll
    for (int g = 0; g < 4; ++g) {
        const float b = bsum[g * 128 + unit];
        bini[g] = (f32x4){b, b, b, b};
    }

    // tuple ownership: lanes 0..31, col = quad&1, one (col,unit) per lane
    const bool owner = (lane < 32);
    const int col = quad & 1;

    float c_ = 0.0f, h0v = 0.0f;
    if (owner) {
        c_  = c0[(size_t)(bb + col) * HID + unit];
        h0v = h0[(size_t)(bb + col) * HID + unit];
    }
    __syncthreads();   // preloads visible

    if (owner)
        hx[0][col][unit] = f2h_bits(h0v * (1.0f - (float)dls[0][col]));
    __syncthreads();

    float hl = 0.0f;

    // hx frags (A operand): zero-init ONCE; only lanes n<COLS ever overwrite.
    h8 bf[5];
    #pragma unroll
    for (int kt = 0; kt < 5; ++kt) bf[kt] = (h8)(_Float16)0.0f;

    #pragma unroll 1
    for (int s = 0; s < T_STEPS; ++s) {
        const int buf = s & 1;

        // predicated frag load: 8 active lanes (n<2), zero conflicts.
        // bf[0..3] = h from hx double buffer; bf[4] = x from static stage.
        if (n < COLS) {
            #pragma unroll
            for (int kt = 0; kt < 4; ++kt)
                bf[kt] = *reinterpret_cast<const h8*>(&hx[buf][n][kt * 32 + quad * 8]);
            bf[4] = *reinterpret_cast<const h8*>(&xls[s][n][quad * 8]);
        }

        // masks from LDS (broadcast reads, hidden under MFMA)
        const int sn = (s + 1 < T_STEPS) ? s + 1 : T_STEPS - 1;
        const int m_cur = dls[s][col];
        const int m_nxt = dls[sn][col];

        // MFMA: gates^T = hx @ Wc^T + b   (swapped operands, bias via C-init)
        f32x4 acc[4];
        #pragma unroll
        for (int g = 0; g < 4; ++g) acc[g] = bini[g];
        #pragma unroll
        for (int kt = 0; kt < 5; ++kt)
            #pragma unroll
            for (int g = 0; g < 4; ++g)
                acc[g] = __builtin_amdgcn_mfma_f32_16x16x32_f16(
                    bf[kt], wf[g][kt], acc[g], 0, 0, 0);

        // redistribute: lane L<32 takes acc[g][L>>4] of lane L&15
        float g4[4];
        #pragma unroll
        for (int g = 0; g < 4; ++g) {
            const float t0 = swz16(acc[g][0]);
            const float t1 = swz16(acc[g][1]);
            g4[g] = (lane & 16) ? t1 : t0;
        }

        // gate math: issued once per wave, 32 parallel tuples
        if (owner) {
            const float cn = sigf(g4[1]) * (c_ * (1.0f - (float)m_cur))
                           + sigf(g4[0]) * tanh_fast(g4[2]);
            const float hn = sigf(g4[3]) * tanh_fast(cn);
            c_ = cn; hl = hn;
            out[(size_t)(s * BATCH + bb + col) * HID + unit] = hn;
            hx[buf ^ 1][col][unit] = f2h_bits(hn * (1.0f - (float)m_nxt));
        }
        // LDS-only barrier: hx[buf^1] visible; out-store ack stays in flight
        barrier_lds_only();
    }

    const size_t base = (size_t)TBROWS * HID;
    if (owner) {
        out[base + (size_t)(bb + col) * HID + unit] = hl;
        out[base + (size_t)BATCH * HID + (size_t)(bb + col) * HID + unit] = c_;
    }
}

// ===========================================================================
extern "C" void kernel_launch(void* const* d_in, const int* in_sizes, int n_in,
                              void* d_out, int out_size, void* d_ws, size_t ws_size,
                              hipStream_t stream) {
    const float* img  = (const float*)d_in[0];
    const float* loc  = (const float*)d_in[1];
    const float* msg  = (const float*)d_in[2];
    const int*   done = (const int*)d_in[3];
    const float* h0   = (const float*)d_in[4];
    const float* c0   = (const float*)d_in[5];
    const float* W1   = (const float*)d_in[6];
    const float* B1   = (const float*)d_in[7];
    const float* W2   = (const float*)d_in[8];
    const float* B2   = (const float*)d_in[9];
    const float* W3   = (const float*)d_in[10];
    const float* B3   = (const float*)d_in[11];
    const float* W4   = (const float*)d_in[12];
    const float* B4   = (const float*)d_in[13];
    const float* Wl   = (const float*)d_in[14];
    const float* Bl   = (const float*)d_in[15];
    const float* Wm   = (const float*)d_in[16];
    const float* Bm   = (const float*)d_in[17];
    const float* Wih  = (const float*)d_in[18];
    const float* bih  = (const float*)d_in[19];
    const float* Whh  = (const float*)d_in[20];
    const float* bhh  = (const float*)d_in[21];

    // workspace layout
    char* wsb = (char*)d_ws;
    unsigned short* xcat_h = (unsigned short*)wsb;                   // 8 388 608 B
    unsigned short* w1f = (unsigned short*)(wsb + (size_t)TBROWS * XH_STRIDE * 2);
    unsigned short* w2f = w1f + NE1;
    unsigned short* w3f = w2f + NE2;
    unsigned short* w4f = w3f + NE3;
    unsigned short* wcf = w4f + NE4;
    float*          bsum = (float*)(wcf + NWC);

    float* out = (float*)d_out;

    prep_kernel<<<(PREP_TOTAL + 255) / 256, 256, 0, stream>>>(
        W1, W2, W3, W4, Wih, bih, Whh, bhh,
        w1f, w2f, w3f, w4f, wcf, bsum);
    encoder_kernel<<<TBROWS / EBLK, 512, 0, stream>>>(
        img, loc, msg, done, B1, B2, B3, B4, Wl, Bl, Wm, Bm,
        w1f, w2f, w3f, w4f, xcat_h);
    lstm_kernel<<<BATCH / COLS, 512, 0, stream>>>(
        xcat_h, done, h0, c0, wcf, bsum, out);
}

// Round 10
// 336.688 us; speedup vs baseline: 1.0766x; 1.0766x over previous
//
#include <hip/hip_runtime.h>
#include <hip/hip_bf16.h>

#define T_STEPS 256
#define BATCH   512
#define HID     128
#define TBROWS  (T_STEPS * BATCH)
#define XH_STRIDE 32          // xcat as f16, 32 ushorts per row (24 used)

typedef short  bh8   __attribute__((ext_vector_type(8)));   // 8 bf16 (MFMA A/B frag)
typedef _Float16 h8  __attribute__((ext_vector_type(8)));   // 8 f16  (MFMA A/B frag)
typedef float  f32x4 __attribute__((ext_vector_type(4)));   // MFMA C/D frag

__device__ __forceinline__ unsigned short f2bf_bits(float x) {
    union { float f; unsigned int u; } a; a.f = x;
    unsigned int r = a.u + 0x7fffu + ((a.u >> 16) & 1u);   // RNE
    return (unsigned short)(r >> 16);
}
__device__ __forceinline__ unsigned short f2h_bits(float x) {
    union { _Float16 h; unsigned short u; } z; z.h = (_Float16)x; return z.u;
}
__device__ __forceinline__ unsigned int pack2h(float a, float b) {
    union { _Float16 h[2]; unsigned int u; } z;
    z.h[0] = (_Float16)a; z.h[1] = (_Float16)b; return z.u;
}
__device__ __forceinline__ unsigned int pack2bf(float a, float b) {
    return (unsigned int)f2bf_bits(a) | ((unsigned int)f2bf_bits(b) << 16);
}

#if __has_builtin(__builtin_amdgcn_rcpf)
__device__ __forceinline__ float frcp(float x) { return __builtin_amdgcn_rcpf(x); }
#else
__device__ __forceinline__ float frcp(float x) { return 1.0f / x; }
#endif
#if __has_builtin(__builtin_amdgcn_exp2f)
__device__ __forceinline__ float fexp2(float x) { return __builtin_amdgcn_exp2f(x); }
#else
__device__ __forceinline__ float fexp2(float x) { return __expf(x * 0.6931471806f); }
#endif
#define LOG2E 1.442695041f
__device__ __forceinline__ float sigf(float x) {
    return frcp(1.0f + fexp2(-x * LOG2E));
}
__device__ __forceinline__ float tanh_fast(float x) {
    return fmaf(-2.0f, frcp(1.0f + fexp2(x * (2.0f * LOG2E))), 1.0f);
}

// ds_swizzle BitMode: src_lane = lane & 0xF (within each 32-half)
__device__ __forceinline__ float swz16(float v) {
    return __int_as_float(
        __builtin_amdgcn_ds_swizzle(__float_as_int(v), 0x000F));
}

// Raw workgroup barrier that drains ONLY LDS ops (lgkmcnt), leaving global
// stores/loads in flight (out-store acks never gate the scan step).
__device__ __forceinline__ void barrier_lds_only() {
    asm volatile("s_waitcnt lgkmcnt(0)" ::: "memory");
    __builtin_amdgcn_s_barrier();
    asm volatile("" ::: "memory");
}

// ===========================================================================
// Prep (unchanged): bf16 frag blobs for MLP, f16 frag blob for the LSTM
// combined weight Wc[512x160] (k<128 Whh, 128<=k<152 Wih, else 0), fused
// gate bias. Frag layout (A and B share the pattern on 16x16x32):
//   blob[(tile*KT + kt)*512 + lane*8 + j] = W[tile*16 + (lane&15)][kt*32 + (lane>>4)*8 + j]
// ===========================================================================
__device__ __forceinline__ void fragstore(unsigned short* dst, const float* W,
                                          int i, int NT, int Kreal) {
    const int j    = i & 7;
    const int lane = (i >> 3) & 63;
    const int ts   = i >> 9;
    const int nt   = ts % NT;
    const int ks   = ts / NT;
    const int n = nt * 16 + (lane & 15);
    const int k = ks * 32 + (lane >> 4) * 8 + j;
    dst[i] = (k < Kreal) ? f2bf_bits(W[n * Kreal + k]) : (unsigned short)0;
}

#define NE1 8192     // 16 tiles * 512
#define NE2 65536    // 8 kt * 16 tiles * 512
#define NE3 32768    // 8 * 8 * 512
#define NE4 2048     // 4 * 1 * 512
#define NWC 81920    // 32 mtiles * 5 ktiles * 64 * 8  (LSTM frags, f16)
#define NBS 512
#define PREP_TOTAL (NE1 + NE2 + NE3 + NE4 + NWC + NBS)   // 190976

__global__ __launch_bounds__(256) void prep_kernel(
    const float* __restrict__ W1, const float* __restrict__ W2,
    const float* __restrict__ W3, const float* __restrict__ W4,
    const float* __restrict__ Wih, const float* __restrict__ bih,
    const float* __restrict__ Whh, const float* __restrict__ bhh,
    unsigned short* __restrict__ w1f, unsigned short* __restrict__ w2f,
    unsigned short* __restrict__ w3f, unsigned short* __restrict__ w4f,
    unsigned short* __restrict__ wcf, float* __restrict__ bsum)
{
    int i = blockIdx.x * 256 + threadIdx.x;
    if (i < NE1) { fragstore(w1f, W1, i, 16, 25); return; }
    i -= NE1;
    if (i < NE2) { fragstore(w2f, W2, i, 16, 256); return; }
    i -= NE2;
    if (i < NE3) { fragstore(w3f, W3, i, 8, 256); return; }
    i -= NE3;
    if (i < NE4) { fragstore(w4f, W4, i, 1, 128); return; }
    i -= NE4;
    if (i < NWC) {
        const int j    = i & 7;
        const int lane = (i >> 3) & 63;
        const int ts   = i >> 9;          // mt*5 + kt
        const int mt   = ts / 5;
        const int kt   = ts - mt * 5;
        const int m = mt * 16 + (lane & 15);
        const int k = kt * 32 + (lane >> 4) * 8 + j;
        float v = 0.0f;
        if (k < 128)      v = Whh[m * 128 + k];
        else if (k < 152) v = Wih[m * 24 + (k - 128)];
        wcf[i] = f2h_bits(v);
        return;
    }
    i -= NWC;
    if (i < NBS) bsum[i] = bih[i] + bhh[i];
}

// ===========================================================================
// Encoder v7 (8-wave mt-split, high TLP): block = 64 samples, 512 thr
// (8 waves). Wave w owns L1/L2 mtiles {2w,2w+1}, L3 mtile w; L4 on waves
// 0..3 (one sample-group each). Per-wave weight-frag loads drop 56->30 and
// acc halves vs v3 -> VGPR <= 128, LDS = img stage 6.5KB + 2 act buffers
// 67.6KB = 74KB  => 2 blocks/CU x 8 waves = 4 waves/SIMD (v3 had 2/SIMD;
// that latency exposure was the measured ~120us-over-floor). img staged
// once per block via a perfectly-coalesced 1600-float burst (v3: each wave
// issued 32 scattered 100B-stride scalar loads).
// ===========================================================================
#define ASTRIDE 264
#define ESAMP 64

__global__ __launch_bounds__(512, 4) void encoder_kernel(
    const float* __restrict__ img,
    const float* __restrict__ loc,
    const float* __restrict__ msg,
    const int*   __restrict__ done,
    const float* __restrict__ B1, const float* __restrict__ B2,
    const float* __restrict__ B3, const float* __restrict__ B4,
    const float* __restrict__ Wl, const float* __restrict__ Bl,
    const float* __restrict__ Wm, const float* __restrict__ Bm,
    const unsigned short* __restrict__ w1f, const unsigned short* __restrict__ w2f,
    const unsigned short* __restrict__ w3f, const unsigned short* __restrict__ w4f,
    unsigned short* __restrict__ xcat_h)
{
    __shared__ float imgLS[ESAMP][26];                              // 6.5 KB
    __shared__ __align__(16) unsigned short actA[ESAMP][ASTRIDE];   // 33.8 KB
    __shared__ __align__(16) unsigned short actB[ESAMP][ASTRIDE];   // 33.8 KB

    const int tid  = threadIdx.x;
    const int w    = tid >> 6;        // wave 0..7
    const int lane = tid & 63;
    const int n    = lane & 15;       // sample within group
    const int quad = lane >> 4;
    const int row0 = blockIdx.x * ESAMP;

    // coalesced img stage: 64 rows x 25 floats, contiguous burst
    for (int i = tid; i < ESAMP * 25; i += 512)
        imgLS[i / 25][i % 25] = img[(size_t)row0 * 25 + i];

    // loc/msg encoders: 64 samples per block, 1 thread each
    if (tid < ESAMP) {
        const int grow = row0 + tid;
        const float l0 = loc[(size_t)grow * 2 + 0] * 0.1f;
        const float l1 = loc[(size_t)grow * 2 + 1] * 0.1f;
        #pragma unroll
        for (int c = 0; c < 4; ++c)
            xcat_h[(size_t)grow * XH_STRIDE + 16 + c] =
                f2h_bits(fmaf(Wl[c * 2 + 0], l0, fmaf(Wl[c * 2 + 1], l1, Bl[c])));
        const float mm = (1.0f - (float)done[grow]) * msg[grow];
        #pragma unroll
        for (int c = 0; c < 4; ++c)
            xcat_h[(size_t)grow * XH_STRIDE + 20 + c] =
                f2h_bits(fmaxf(fmaf(Wm[c], mm, Bm[c]), 0.0f));
    }
    __syncthreads();

    const f32x4 zero4 = {0.0f, 0.0f, 0.0f, 0.0f};

    // ---- L1: 25(pad32) -> 256; wave w owns mtiles 2w, 2w+1 ----
    {
        bh8 bimg[4];
        #pragma unroll
        for (int sg = 0; sg < 4; ++sg)
            #pragma unroll
            for (int j = 0; j < 8; ++j) {
                const int k = quad * 8 + j;
                const float v = (k < 25) ? imgLS[sg * 16 + n][k] * (1.0f / 255.0f) : 0.0f;
                bimg[sg][j] = (short)f2bf_bits(v);
            }
        #pragma unroll
        for (int mt = 0; mt < 2; ++mt) {
            const int mtg = 2 * w + mt;
            const bh8 a = *reinterpret_cast<const bh8*>(w1f + (size_t)(mtg * 64 + lane) * 8);
            f32x4 acc[4];
            #pragma unroll
            for (int sg = 0; sg < 4; ++sg)
                acc[sg] = __builtin_amdgcn_mfma_f32_16x16x32_bf16(a, bimg[sg], zero4, 0, 0, 0);
            const float4 bv = *reinterpret_cast<const float4*>(B1 + mtg * 16 + quad * 4);
            #pragma unroll
            for (int sg = 0; sg < 4; ++sg) {
                const float v0 = fmaxf(acc[sg][0] + bv.x, 0.0f);
                const float v1 = fmaxf(acc[sg][1] + bv.y, 0.0f);
                const float v2 = fmaxf(acc[sg][2] + bv.z, 0.0f);
                const float v3 = fmaxf(acc[sg][3] + bv.w, 0.0f);
                uint2 pk; pk.x = pack2bf(v0, v1); pk.y = pack2bf(v2, v3);
                *reinterpret_cast<uint2*>(&actA[sg * 16 + n][mtg * 16 + quad * 4]) = pk;
            }
        }
    }
    __syncthreads();

    // ---- L2: 256 -> 256; wave w owns mtiles 2w, 2w+1 ----
    {
        f32x4 a2[2][4];
        #pragma unroll
        for (int mt = 0; mt < 2; ++mt)
            #pragma unroll
            for (int sg = 0; sg < 4; ++sg) a2[mt][sg] = zero4;
        #pragma unroll
        for (int kt = 0; kt < 8; ++kt) {
            bh8 b[4];
            #pragma unroll
            for (int sg = 0; sg < 4; ++sg)
                b[sg] = *reinterpret_cast<const bh8*>(&actA[sg * 16 + n][kt * 32 + quad * 8]);
            #pragma unroll
            for (int mt = 0; mt < 2; ++mt) {
                const int mtg = 2 * w + mt;
                const bh8 a = *reinterpret_cast<const bh8*>(
                    w2f + (size_t)((kt * 16 + mtg) * 64 + lane) * 8);
                #pragma unroll
                for (int sg = 0; sg < 4; ++sg)
                    a2[mt][sg] = __builtin_amdgcn_mfma_f32_16x16x32_bf16(a, b[sg], a2[mt][sg], 0, 0, 0);
            }
        }
        #pragma unroll
        for (int mt = 0; mt < 2; ++mt) {
            const int mtg = 2 * w + mt;
            const float4 bv = *reinterpret_cast<const float4*>(B2 + mtg * 16 + quad * 4);
            #pragma unroll
            for (int sg = 0; sg < 4; ++sg) {
                const float v0 = fmaxf(a2[mt][sg][0] + bv.x, 0.0f);
                const float v1 = fmaxf(a2[mt][sg][1] + bv.y, 0.0f);
                const float v2 = fmaxf(a2[mt][sg][2] + bv.z, 0.0f);
                const float v3 = fmaxf(a2[mt][sg][3] + bv.w, 0.0f);
                uint2 pk; pk.x = pack2bf(v0, v1); pk.y = pack2bf(v2, v3);
                *reinterpret_cast<uint2*>(&actB[sg * 16 + n][mtg * 16 + quad * 4]) = pk;
            }
        }
    }
    __syncthreads();

    // ---- L3: 256 -> 128; wave w owns mtile w ----
    {
        f32x4 a3[4];
        #pragma unroll
        for (int sg = 0; sg < 4; ++sg) a3[sg] = zero4;
        #pragma unroll
        for (int kt = 0; kt < 8; ++kt) {
            bh8 b[4];
            #pragma unroll
            for (int sg = 0; sg < 4; ++sg)
                b[sg] = *reinterpret_cast<const bh8*>(&actB[sg * 16 + n][kt * 32 + quad * 8]);
            const bh8 a = *reinterpret_cast<const bh8*>(
                w3f + (size_t)((kt * 8 + w) * 64 + lane) * 8);
            #pragma unroll
            for (int sg = 0; sg < 4; ++sg)
                a3[sg] = __builtin_amdgcn_mfma_f32_16x16x32_bf16(a, b[sg], a3[sg], 0, 0, 0);
        }
        const float4 bv = *reinterpret_cast<const float4*>(B3 + w * 16 + quad * 4);
        #pragma unroll
        for (int sg = 0; sg < 4; ++sg) {
            const float v0 = fmaxf(a3[sg][0] + bv.x, 0.0f);
            const float v1 = fmaxf(a3[sg][1] + bv.y, 0.0f);
            const float v2 = fmaxf(a3[sg][2] + bv.z, 0.0f);
            const float v3 = fmaxf(a3[sg][3] + bv.w, 0.0f);
            uint2 pk; pk.x = pack2bf(v0, v1); pk.y = pack2bf(v2, v3);
            *reinterpret_cast<uint2*>(&actA[sg * 16 + n][w * 16 + quad * 4]) = pk;
        }
    }
    __syncthreads();

    // ---- L4: 128 -> 16; waves 0..3, sample-group = w ----
    if (w < 4) {
        f32x4 a4 = zero4;
        #pragma unroll
        for (int kt = 0; kt < 4; ++kt) {
            const bh8 b = *reinterpret_cast<const bh8*>(&actA[w * 16 + n][kt * 32 + quad * 8]);
            const bh8 a = *reinterpret_cast<const bh8*>(w4f + (size_t)(kt * 64 + lane) * 8);
            a4 = __builtin_amdgcn_mfma_f32_16x16x32_bf16(a, b, a4, 0, 0, 0);
        }
        const float4 bv = *reinterpret_cast<const float4*>(B4 + quad * 4);
        const int grow = row0 + w * 16 + n;
        const float v0 = fmaxf(a4[0] + bv.x, 0.0f);
        const float v1 = fmaxf(a4[1] + bv.y, 0.0f);
        const float v2 = fmaxf(a4[2] + bv.z, 0.0f);
        const float v3 = fmaxf(a4[3] + bv.w, 0.0f);
        uint2 pk; pk.x = pack2h(v0, v1); pk.y = pack2h(v2, v3);
        *reinterpret_cast<uint2*>(xcat_h + (size_t)grow * XH_STRIDE + quad * 4) = pk;
    }
}

// ===========================================================================
// LSTM scan v8 (unchanged, ~197 us): 256 blocks x 2 cols, 512 threads
// (8 waves). Swapped-operand MFMA, predicated 8-lane hx frag loads,
// ds_swizzle gate redistribution, full x/done LDS preload, lgkm-only
// barrier. Near structural floor for this decomposition (~40 MFMA/SIMD/step
// at ~17-19 cy + serial chain).
// ===========================================================================
#define COLS 2

__global__ __launch_bounds__(512) void lstm_kernel(
    const unsigned short* __restrict__ xcat_h,
    const int*   __restrict__ done,
    const float* __restrict__ h0,
    const float* __restrict__ c0,
    const unsigned short* __restrict__ wcf,   // frag blob [32][5][64][8] f16
    const float* __restrict__ bsum,           // [512] = bih + bhh
    float* __restrict__ out)
{
    __shared__ __align__(16) unsigned short xls[T_STEPS][COLS][32];  // 32 KB
    __shared__ __align__(16) unsigned short hx[2][COLS][HID];        // 1 KB
    __shared__ int dls[T_STEPS][COLS];                               // 2 KB

    const int tid  = threadIdx.x;
    const int w    = tid >> 6;        // wave 0..7
    const int lane = tid & 63;
    const int n    = lane & 15;
    const int quad = lane >> 4;
    const int bb   = blockIdx.x * COLS;

    // ---- one-time preload: x sequence (k=128..159 of the frag, pad zeroed)
    for (int i = tid; i < T_STEPS * COLS * 16; i += 512) {
        const int dw = i & 15;            // dword within 32-short row
        const int rc = i >> 4;            // step*COLS + col
        const int st = rc >> 1, cl = rc & 1;
        unsigned int v = 0u;
        if (dw < 12)
            v = *reinterpret_cast<const unsigned int*>(
                xcat_h + (size_t)(st * BATCH + bb + cl) * XH_STRIDE + dw * 2);
        *reinterpret_cast<unsigned int*>(&xls[st][cl][dw * 2]) = v;
    }
    // ---- one-time preload: done sequence
    if (tid < T_STEPS * COLS) {
        const int st = tid >> 1, cl = tid & 1;
        dls[st][cl] = done[st * BATCH + bb + cl];
    }

    // weight frags (B operand of the swapped MFMA): wave w covers units
    // w*16..w*16+15 for gate g via mtile g*8+w.  (80 VGPRs)
    h8 wf[4][5];
    #pragma unroll
    for (int g = 0; g < 4; ++g)
        #pragma unroll
        for (int kt = 0; kt < 5; ++kt)
            wf[g][kt] = *reinterpret_cast<const h8*>(
                wcf + (size_t)(((g * 8 + w) * 5 + kt) * 64 + lane) * 8);

    // bias C-init: C col (=lane&15) is the unit dim -> per-lane splat
    const int unit = w * 16 + n;
    f32x4 bini[4];
    #pragma unroll
    for (int g = 0; g < 4; ++g) {
        const float b = bsum[g * 128 + unit];
        bini[g] = (f32x4){b, b, b, b};
    }

    // tuple ownership: lanes 0..31, col = quad&1, one (col,unit) per lane
    const bool owner = (lane < 32);
    const int col = quad & 1;

    float c_ = 0.0f, h0v = 0.0f;
    if (owner) {
        c_  = c0[(size_t)(bb + col) * HID + unit];
        h0v = h0[(size_t)(bb + col) * HID + unit];
    }
    __syncthreads();   // preloads visible

    if (owner)
        hx[0][col][unit] = f2h_bits(h0v * (1.0f - (float)dls[0][col]));
    __syncthreads();

    float hl = 0.0f;

    // hx frags (A operand): zero-init ONCE; only lanes n<COLS ever overwrite.
    h8 bf[5];
    #pragma unroll
    for (int kt = 0; kt < 5; ++kt) bf[kt] = (h8)(_Float16)0.0f;

    #pragma unroll 1
    for (int s = 0; s < T_STEPS; ++s) {
        const int buf = s & 1;

        // predicated frag load: 8 active lanes (n<2), zero conflicts.
        // bf[0..3] = h from hx double buffer; bf[4] = x from static stage.
        if (n < COLS) {
            #pragma unroll
            for (int kt = 0; kt < 4; ++kt)
                bf[kt] = *reinterpret_cast<const h8*>(&hx[buf][n][kt * 32 + quad * 8]);
            bf[4] = *reinterpret_cast<const h8*>(&xls[s][n][quad * 8]);
        }

        // masks from LDS (broadcast reads, hidden under MFMA)
        const int sn = (s + 1 < T_STEPS) ? s + 1 : T_STEPS - 1;
        const int m_cur = dls[s][col];
        const int m_nxt = dls[sn][col];

        // MFMA: gates^T = hx @ Wc^T + b   (swapped operands, bias via C-init)
        f32x4 acc[4];
        #pragma unroll
        for (int g = 0; g < 4; ++g) acc[g] = bini[g];
        #pragma unroll
        for (int kt = 0; kt < 5; ++kt)
            #pragma unroll
            for (int g = 0; g < 4; ++g)
                acc[g] = __builtin_amdgcn_mfma_f32_16x16x32_f16(
                    bf[kt], wf[g][kt], acc[g], 0, 0, 0);

        // redistribute: lane L<32 takes acc[g][L>>4] of lane L&15
        float g4[4];
        #pragma unroll
        for (int g = 0; g < 4; ++g) {
            const float t0 = swz16(acc[g][0]);
            const float t1 = swz16(acc[g][1]);
            g4[g] = (lane & 16) ? t1 : t0;
        }

        // gate math: issued once per wave, 32 parallel tuples
        if (owner) {
            const float cn = sigf(g4[1]) * (c_ * (1.0f - (float)m_cur))
                           + sigf(g4[0]) * tanh_fast(g4[2]);
            const float hn = sigf(g4[3]) * tanh_fast(cn);
            c_ = cn; hl = hn;
            out[(size_t)(s * BATCH + bb + col) * HID + unit] = hn;
            hx[buf ^ 1][col][unit] = f2h_bits(hn * (1.0f - (float)m_nxt));
        }
        // LDS-only barrier: hx[buf^1] visible; out-store ack stays in flight
        barrier_lds_only();
    }

    const size_t base = (size_t)TBROWS * HID;
    if (owner) {
        out[base + (size_t)(bb + col) * HID + unit] = hl;
        out[base + (size_t)BATCH * HID + (size_t)(bb + col) * HID + unit] = c_;
    }
}

// ===========================================================================
extern "C" void kernel_launch(void* const* d_in, const int* in_sizes, int n_in,
                              void* d_out, int out_size, void* d_ws, size_t ws_size,
                              hipStream_t stream) {
    const float* img  = (const float*)d_in[0];
    const float* loc  = (const float*)d_in[1];
    const float* msg  = (const float*)d_in[2];
    const int*   done = (const int*)d_in[3];
    const float* h0   = (const float*)d_in[4];
    const float* c0   = (const float*)d_in[5];
    const float* W1   = (const float*)d_in[6];
    const float* B1   = (const float*)d_in[7];
    const float* W2   = (const float*)d_in[8];
    const float* B2   = (const float*)d_in[9];
    const float* W3   = (const float*)d_in[10];
    const float* B3   = (const float*)d_in[11];
    const float* W4   = (const float*)d_in[12];
    const float* B4   = (const float*)d_in[13];
    const float* Wl   = (const float*)d_in[14];
    const float* Bl   = (const float*)d_in[15];
    const float* Wm   = (const float*)d_in[16];
    const float* Bm   = (const float*)d_in[17];
    const float* Wih  = (const float*)d_in[18];
    const float* bih  = (const float*)d_in[19];
    const float* Whh  = (const float*)d_in[20];
    const float* bhh  = (const float*)d_in[21];

    // workspace layout
    char* wsb = (char*)d_ws;
    unsigned short* xcat_h = (unsigned short*)wsb;                   // 8 388 608 B
    unsigned short* w1f = (unsigned short*)(wsb + (size_t)TBROWS * XH_STRIDE * 2);
    unsigned short* w2f = w1f + NE1;
    unsigned short* w3f = w2f + NE2;
    unsigned short* w4f = w3f + NE3;
    unsigned short* wcf = w4f + NE4;
    float*          bsum = (float*)(wcf + NWC);

    float* out = (float*)d_out;

    prep_kernel<<<(PREP_TOTAL + 255) / 256, 256, 0, stream>>>(
        W1, W2, W3, W4, Wih, bih, Whh, bhh,
        w1f, w2f, w3f, w4f, wcf, bsum);
    encoder_kernel<<<TBROWS / ESAMP, 512, 0, stream>>>(
        img, loc, msg, done, B1, B2, B3, B4, Wl, Bl, Wm, Bm,
        w1f, w2f, w3f, w4f, xcat_h);
    lstm_kernel<<<BATCH / COLS, 512, 0, stream>>>(
        xcat_h, done, h0, c0, wcf, bsum, out);
}